// Round 1
// baseline (113.920 us; speedup 1.0000x reference)
//
#include <hip/hip_runtime.h>

typedef __bf16 bf16x4 __attribute__((ext_vector_type(4)));
typedef __bf16 bf16x8 __attribute__((ext_vector_type(8)));
typedef float  f32x4  __attribute__((ext_vector_type(4)));

#define XS 68   // LDS row stride (bf16 elems) for X tile: 64 + 4 pad

// Grid = 512 (one block per batch row b), 256 threads (4 waves).
// Single fused kernel:
//   - X@Wc (bf16 MFMA) + LeakyReLU + max-over-e + sum-over-S + fc1  (per block)
//   - last block to finish runs BatchNorm + LeakyReLU + fc2 (device-scope
//     atomic counter + release/acquire fences for cross-XCD out1 visibility)
// Changes vs prev: 2-deep register prefetch of X tiles (HBM latency ~900cy
// gets ~2 compute phases of slack), double-buffered X LDS tile -> 1 barrier
// per s-tile, bn_fc2 dispatch eliminated.
__global__ __launch_bounds__(256, 2)
void fused_all(const float* __restrict__ X, const float* __restrict__ Wc,
               const float* __restrict__ fc1_w, const float* __restrict__ fc1_b,
               const float* __restrict__ gamma, const float* __restrict__ beta,
               const float* __restrict__ fc2_w, const float* __restrict__ fc2_b,
               float* __restrict__ out1, unsigned* __restrict__ cnt,
               float* __restrict__ out)
{
    __shared__ __bf16 xlds[2][64 * XS];   // 17408 B, double-buffered X tile
    __shared__ float  t0row[64];
    __shared__ float  redsum[8][32];
    __shared__ float  redsq[8][32];
    __shared__ float  sa[32], sc[32];
    __shared__ int    lastflag;

    const int tid  = threadIdx.x;
    const int b    = blockIdx.x;
    const int wave = tid >> 6;
    const int lane = tid & 63;
    const int n    = lane & 15;
    const int q    = lane >> 4;

    const float4* xg = (const float4*)(X + (size_t)b * 256 * 64);

    // ---- prefetch X tiles 0 and 1 into registers (2-deep) ----
    float4 xv[2][4];
    #pragma unroll
    for (int i = 0; i < 4; ++i) xv[0][i] = xg[tid + i * 256];
    #pragma unroll
    for (int i = 0; i < 4; ++i) xv[1][i] = xg[1024 + tid + i * 256];

    // ---- B fragments straight to registers: bf0/bf1[e][j] = Wc[k][c] ----
    // lane (n,q) holds cols c = e*64 + wave*16 + n, k = q*8+j (+32 for bf1).
    // Wc is 131 KB -> L2-hot after first touch; cvt work overlaps X flight.
    bf16x8 bf0[8], bf1[8];
    {
        const float* wbase = Wc + (q * 8) * 512 + wave * 16 + n;
        #pragma unroll
        for (int e = 0; e < 8; ++e) {
            const float* p = wbase + e * 64;
            #pragma unroll
            for (int j = 0; j < 8; ++j) {
                bf0[e][j] = (__bf16)p[j * 512];
                bf1[e][j] = (__bf16)p[(j + 32) * 512];
            }
        }
    }

    float hsum = 0.0f;   // running sum over S for col h = wave*16 + n

    #pragma unroll
    for (int st = 0; st < 4; ++st) {
        const int pbuf = st & 1;

        // ---- commit prefetched tile st to LDS (fp32 -> bf16) ----
        #pragma unroll
        for (int i = 0; i < 4; ++i) {
            const int p = tid + i * 256;          // float4 index within 16KB tile
            bf16x4 o;
            o[0] = (__bf16)xv[pbuf][i].x; o[1] = (__bf16)xv[pbuf][i].y;
            o[2] = (__bf16)xv[pbuf][i].z; o[3] = (__bf16)xv[pbuf][i].w;
            const int r = p >> 4, ck = p & 15;
            *(bf16x4*)&xlds[pbuf][r * XS + ck * 4] = o;
        }

        // ---- issue tile st+2 loads into the regs just freed ----
        if (st < 2) {
            const float4* xgn = xg + (st + 2) * 1024;
            #pragma unroll
            for (int i = 0; i < 4; ++i) xv[pbuf][i] = xgn[tid + i * 256];
        }

        __syncthreads();   // commit visible; buffer pbuf was last read 2 iters ago -> safe

        // ---- A fragments: 4 row-tiles, k-halves 0..31 / 32..63 ----
        bf16x8 a0[4], a1[4];
        #pragma unroll
        for (int t = 0; t < 4; ++t) {
            const int base = (t * 16 + n) * XS + q * 8;
            bf16x4 p0 = *(const bf16x4*)&xlds[pbuf][base];
            bf16x4 p1 = *(const bf16x4*)&xlds[pbuf][base + 4];
            bf16x4 p2 = *(const bf16x4*)&xlds[pbuf][base + 32];
            bf16x4 p3 = *(const bf16x4*)&xlds[pbuf][base + 36];
            a0[t] = __builtin_shufflevector(p0, p1, 0, 1, 2, 3, 4, 5, 6, 7);
            a1[t] = __builtin_shufflevector(p2, p3, 0, 1, 2, 3, 4, 5, 6, 7);
        }

        float rmax[4][4];
        #pragma unroll
        for (int t = 0; t < 4; ++t)
            #pragma unroll
            for (int r4 = 0; r4 < 4; ++r4) rmax[t][r4] = -3.0e38f;

        #pragma unroll
        for (int e = 0; e < 8; ++e) {
            #pragma unroll
            for (int t = 0; t < 4; ++t) {
                f32x4 acc = {0.f, 0.f, 0.f, 0.f};
                acc = __builtin_amdgcn_mfma_f32_16x16x32_bf16(a0[t], bf0[e], acc, 0, 0, 0);
                acc = __builtin_amdgcn_mfma_f32_16x16x32_bf16(a1[t], bf1[e], acc, 0, 0, 0);
                #pragma unroll
                for (int r4 = 0; r4 < 4; ++r4) {
                    // max(rmax, LeakyReLU(v)) = max3(rmax, v, 0.01*v) -> v_mul + v_max3
                    rmax[t][r4] = fmaxf(rmax[t][r4], fmaxf(acc[r4], 0.01f * acc[r4]));
                }
            }
        }

        // sum this s-tile's 64 rows: 16 rows per lane, butterfly across quads
        float s = 0.f;
        #pragma unroll
        for (int t = 0; t < 4; ++t)
            #pragma unroll
            for (int r4 = 0; r4 < 4; ++r4) s += rmax[t][r4];
        s += __shfl_xor(s, 16);
        s += __shfl_xor(s, 32);
        hsum += s;
        // no trailing barrier: double-buffered LDS, next commit targets other buffer
    }

    if (lane < 16) t0row[wave * 16 + lane] = hsum;
    __syncthreads();

    // ---- fc1 in-block: out1[b][j] = fc1_b[j] + sum_h t0[h] * fc1_w[j][h] ----
    if (wave == 0) {
        const int j = lane & 31, half = lane >> 5;
        float p = 0.f;
        #pragma unroll
        for (int i = 0; i < 32; ++i)
            p += t0row[half * 32 + i] * fc1_w[j * 64 + half * 32 + i];
        p += __shfl_xor(p, 32);
        if (half == 0) out1[b * 32 + j] = p + fc1_b[j];
    }
    __syncthreads();   // out1 store issued (barrier drains vmcnt) before the fence

    // ---- last-block-done: the 512th block to arrive runs BN + fc2 ----
    if (tid == 0) {
        __threadfence();  // release our out1 row to device scope
        unsigned prev = __hip_atomic_fetch_add(cnt, 1u, __ATOMIC_ACQ_REL,
                                               __HIP_MEMORY_SCOPE_AGENT);
        lastflag = (prev == 511) ? 1 : 0;
    }
    __syncthreads();
    if (!lastflag) return;

    __threadfence();  // acquire for all epilogue threads before reading out1

    // BatchNorm batch stats (biased var) over out1[512][32]
    const int j  = tid & 31;
    const int sl = tid >> 5;        // 8 slices of 64 batch rows
    float s = 0.f, ss = 0.f;
    #pragma unroll 8
    for (int i = 0; i < 64; ++i) {
        float v = out1[(sl * 64 + i) * 32 + j];
        s  += v;
        ss += v * v;
    }
    redsum[sl][j] = s;
    redsq[sl][j]  = ss;
    __syncthreads();

    if (tid < 32) {
        float S = 0.f, SS = 0.f;
        #pragma unroll
        for (int i = 0; i < 8; ++i) { S += redsum[i][tid]; SS += redsq[i][tid]; }
        const float mu  = S * (1.0f / 512.0f);
        const float var = SS * (1.0f / 512.0f) - mu * mu;   // biased variance
        const float rs  = rsqrtf(var + 1e-5f);
        const float a   = rs * gamma[tid];
        sa[tid] = a;
        sc[tid] = beta[tid] - mu * a;
    }
    __syncthreads();

    // BN + LeakyReLU + fc2: 2 batch rows per thread (out1 now L2-hot here)
    #pragma unroll
    for (int r = 0; r < 2; ++r) {
        const int row = tid * 2 + r;
        float acc = 0.f;
        #pragma unroll
        for (int jj = 0; jj < 32; ++jj) {
            float v = out1[row * 32 + jj];
            float y = v * sa[jj] + sc[jj];
            y = fmaxf(y, 0.01f * y);    // LeakyReLU
            acc += y * fc2_w[jj];
        }
        out[row] = acc + fc2_b[0];
    }
}

extern "C" void kernel_launch(void* const* d_in, const int* in_sizes, int n_in,
                              void* d_out, int out_size, void* d_ws, size_t ws_size,
                              hipStream_t stream) {
    const float* X      = (const float*)d_in[0];
    const float* Wc     = (const float*)d_in[1];
    const float* fc1_w  = (const float*)d_in[2];
    const float* fc1_b  = (const float*)d_in[3];
    const float* gamma  = (const float*)d_in[4];
    const float* beta   = (const float*)d_in[5];
    const float* fc2_w  = (const float*)d_in[6];
    const float* fc2_b  = (const float*)d_in[7];

    float*    out1 = (float*)d_ws;                          // [512][32] fc1 outputs
    unsigned* cnt  = (unsigned*)((char*)d_ws + 64 * 1024);  // arrival counter

    // ws is poisoned every iteration -> counter must be zeroed (captured memset node)
    hipMemsetAsync(cnt, 0, sizeof(unsigned), stream);
    fused_all<<<512, 256, 0, stream>>>(X, Wc, fc1_w, fc1_b, gamma, beta,
                                       fc2_w, fc2_b, out1, cnt, (float*)d_out);
}

// Round 2
// 98.551 us; speedup vs baseline: 1.1559x; 1.1559x over previous
//
#include <hip/hip_runtime.h>

typedef __bf16 bf16x4 __attribute__((ext_vector_type(4)));
typedef __bf16 bf16x8 __attribute__((ext_vector_type(8)));
typedef float  f32x4  __attribute__((ext_vector_type(4)));

#define XS 68   // LDS row stride (bf16 elems) for X tile: 64 + 4 pad

// Grid = 512 (one block per batch row b), 256 threads (4 waves).
// Two-kernel structure (fused single-kernel + memset node measured 14% WORSE:
// a graph-captured 4-byte hipMemsetAsync costs ~44 us on this harness).
// vs round-0 baseline: 2-deep register prefetch of X tiles + double-buffered
// X LDS tile -> 1 barrier per s-tile instead of 2.
__global__ __launch_bounds__(256, 2)
void fused_main(const float* __restrict__ X, const float* __restrict__ Wc,
                const float* __restrict__ fc1_w, const float* __restrict__ fc1_b,
                float* __restrict__ out1)
{
    __shared__ __bf16 xlds[2][64 * XS];   // 17408 B, double-buffered X tile
    __shared__ float  t0row[64];

    const int tid  = threadIdx.x;
    const int b    = blockIdx.x;
    const int wave = tid >> 6;
    const int lane = tid & 63;
    const int n    = lane & 15;
    const int q    = lane >> 4;

    const float4* xg = (const float4*)(X + (size_t)b * 256 * 64);

    // ---- prefetch X tiles 0 and 1 into registers (2-deep) ----
    float4 xv[2][4];
    #pragma unroll
    for (int i = 0; i < 4; ++i) xv[0][i] = xg[tid + i * 256];
    #pragma unroll
    for (int i = 0; i < 4; ++i) xv[1][i] = xg[1024 + tid + i * 256];

    // ---- B fragments straight to registers: bf0/bf1[e][j] = Wc[k][c] ----
    // lane (n,q) holds cols c = e*64 + wave*16 + n, k = q*8+j (+32 for bf1).
    // Wc is 131 KB -> L2-hot after first touch; cvt work overlaps X flight.
    bf16x8 bf0[8], bf1[8];
    {
        const float* wbase = Wc + (q * 8) * 512 + wave * 16 + n;
        #pragma unroll
        for (int e = 0; e < 8; ++e) {
            const float* p = wbase + e * 64;
            #pragma unroll
            for (int j = 0; j < 8; ++j) {
                bf0[e][j] = (__bf16)p[j * 512];
                bf1[e][j] = (__bf16)p[(j + 32) * 512];
            }
        }
    }

    float hsum = 0.0f;   // running sum over S for col h = wave*16 + n

    #pragma unroll
    for (int st = 0; st < 4; ++st) {
        const int pbuf = st & 1;

        // ---- commit prefetched tile st to LDS (fp32 -> bf16) ----
        // Safe without a trailing barrier: buffer pbuf was last READ in
        // iteration st-2, and barrier(st-1) ordered those reads before us.
        #pragma unroll
        for (int i = 0; i < 4; ++i) {
            const int p = tid + i * 256;          // float4 index within 16KB tile
            bf16x4 o;
            o[0] = (__bf16)xv[pbuf][i].x; o[1] = (__bf16)xv[pbuf][i].y;
            o[2] = (__bf16)xv[pbuf][i].z; o[3] = (__bf16)xv[pbuf][i].w;
            const int r = p >> 4, ck = p & 15;
            *(bf16x4*)&xlds[pbuf][r * XS + ck * 4] = o;
        }

        // ---- issue tile st+2 loads into the regs just freed ----
        if (st < 2) {
            const float4* xgn = xg + (st + 2) * 1024;
            #pragma unroll
            for (int i = 0; i < 4; ++i) xv[pbuf][i] = xgn[tid + i * 256];
        }

        __syncthreads();   // commit(st) visible before reads(st)

        // ---- A fragments: 4 row-tiles, k-halves 0..31 / 32..63 ----
        bf16x8 a0[4], a1[4];
        #pragma unroll
        for (int t = 0; t < 4; ++t) {
            const int base = (t * 16 + n) * XS + q * 8;
            bf16x4 p0 = *(const bf16x4*)&xlds[pbuf][base];
            bf16x4 p1 = *(const bf16x4*)&xlds[pbuf][base + 4];
            bf16x4 p2 = *(const bf16x4*)&xlds[pbuf][base + 32];
            bf16x4 p3 = *(const bf16x4*)&xlds[pbuf][base + 36];
            a0[t] = __builtin_shufflevector(p0, p1, 0, 1, 2, 3, 4, 5, 6, 7);
            a1[t] = __builtin_shufflevector(p2, p3, 0, 1, 2, 3, 4, 5, 6, 7);
        }

        float rmax[4][4];
        #pragma unroll
        for (int t = 0; t < 4; ++t)
            #pragma unroll
            for (int r4 = 0; r4 < 4; ++r4) rmax[t][r4] = -3.0e38f;

        #pragma unroll
        for (int e = 0; e < 8; ++e) {
            #pragma unroll
            for (int t = 0; t < 4; ++t) {
                f32x4 acc = {0.f, 0.f, 0.f, 0.f};
                acc = __builtin_amdgcn_mfma_f32_16x16x32_bf16(a0[t], bf0[e], acc, 0, 0, 0);
                acc = __builtin_amdgcn_mfma_f32_16x16x32_bf16(a1[t], bf1[e], acc, 0, 0, 0);
                #pragma unroll
                for (int r4 = 0; r4 < 4; ++r4) {
                    // max(rmax, LeakyReLU(v)) = max3(rmax, v, 0.01*v) -> v_mul + v_max3
                    rmax[t][r4] = fmaxf(rmax[t][r4], fmaxf(acc[r4], 0.01f * acc[r4]));
                }
            }
        }

        // sum this s-tile's 64 rows: 16 rows per lane, butterfly across quads
        float s = 0.f;
        #pragma unroll
        for (int t = 0; t < 4; ++t)
            #pragma unroll
            for (int r4 = 0; r4 < 4; ++r4) s += rmax[t][r4];
        s += __shfl_xor(s, 16);
        s += __shfl_xor(s, 32);
        hsum += s;
        // no trailing barrier: double-buffered LDS
    }

    if (lane < 16) t0row[wave * 16 + lane] = hsum;
    __syncthreads();

    // ---- fc1 in-block: out1[b][j] = fc1_b[j] + sum_h t0[h] * fc1_w[j][h] ----
    if (wave == 0) {
        const int j = lane & 31, half = lane >> 5;
        float p = 0.f;
        #pragma unroll
        for (int i = 0; i < 32; ++i)
            p += t0row[half * 32 + i] * fc1_w[j * 64 + half * 32 + i];
        p += __shfl_xor(p, 32);
        if (half == 0) out1[b * 32 + j] = p + fc1_b[j];
    }
}

// Single block: BatchNorm (training-mode batch stats, biased var) + LeakyReLU + fc2
__global__ __launch_bounds__(512)
void bn_fc2(const float* __restrict__ out1, const float* __restrict__ gamma,
            const float* __restrict__ beta, const float* __restrict__ fc2_w,
            const float* __restrict__ fc2_b, float* __restrict__ out)
{
    __shared__ float psum[16][32];
    __shared__ float psumsq[16][32];
    __shared__ float sa[32], sc[32];

    const int tid = threadIdx.x;
    const int j   = tid & 31;
    const int sl  = tid >> 5;       // 16 slices of 32 batch rows

    float s = 0.f, ss = 0.f;
    #pragma unroll
    for (int i = 0; i < 32; ++i) {
        float v = out1[(sl * 32 + i) * 32 + j];
        s  += v;
        ss += v * v;
    }
    psum[sl][j]   = s;
    psumsq[sl][j] = ss;
    __syncthreads();

    if (tid < 32) {
        float S = 0.f, SS = 0.f;
        #pragma unroll
        for (int i = 0; i < 16; ++i) { S += psum[i][tid]; SS += psumsq[i][tid]; }
        const float mu  = S * (1.0f / 512.0f);
        const float var = SS * (1.0f / 512.0f) - mu * mu;   // biased variance
        const float rs  = rsqrtf(var + 1e-5f);
        const float a   = rs * gamma[tid];
        sa[tid] = a;
        sc[tid] = beta[tid] - mu * a;
    }
    __syncthreads();

    // one thread per batch row
    float acc = 0.f;
    #pragma unroll
    for (int jj = 0; jj < 32; ++jj) {
        float v = out1[tid * 32 + jj];
        float y = v * sa[jj] + sc[jj];
        y = fmaxf(y, 0.01f * y);    // LeakyReLU
        acc += y * fc2_w[jj];
    }
    out[tid] = acc + fc2_b[0];
}

extern "C" void kernel_launch(void* const* d_in, const int* in_sizes, int n_in,
                              void* d_out, int out_size, void* d_ws, size_t ws_size,
                              hipStream_t stream) {
    const float* X      = (const float*)d_in[0];
    const float* Wc     = (const float*)d_in[1];
    const float* fc1_w  = (const float*)d_in[2];
    const float* fc1_b  = (const float*)d_in[3];
    const float* gamma  = (const float*)d_in[4];
    const float* beta   = (const float*)d_in[5];
    const float* fc2_w  = (const float*)d_in[6];
    const float* fc2_b  = (const float*)d_in[7];

    float* out1 = (float*)d_ws;   // [512][32] fc1 outputs, 64 KB

    fused_main<<<512, 256, 0, stream>>>(X, Wc, fc1_w, fc1_b, out1);
    bn_fc2<<<1, 512, 0, stream>>>(out1, gamma, beta, fc2_w, fc2_b, (float*)d_out);
}